// Round 4
// baseline (1149.480 us; speedup 1.0000x reference)
//
#include <hip/hip_runtime.h>

#define NFEAT 128
#define HID 16
#define NOUT 2
#define NGRAPH 64

#define BSH 9                      // bucket shift: 512 nodes/bucket
#define BN 512                     // nodes per bucket
#define NBUCK 196                  // ceil(100000/512)
#define NCB 512                    // count/scatter chunks
#define GCNT_TOT (NBUCK * NCB)     // 100352 = 1024*98
#define SPLITS_A 4
#define SPLITS_E 4
#define NPART (NBUCK * SPLITS_E)   // 784 partial rows
#define PSTRIDE 192                // 128 sums + 64 counts
#define AST 17                     // padded LDS row stride (floats) for k_agg
#define E2ST 3                     // padded LDS row stride for e2pool

// ---------------- init: zero agg1 ------------------------------------------
__global__ __launch_bounds__(256) void k_init(float* agg1, int N) {
    int i = blockIdx.x * 256 + threadIdx.x;
    if (i < N * HID) agg1[i] = 0.0f;
}

// ---------------- count: per-(bucket, chunk) histogram ---------------------
__global__ __launch_bounds__(256) void k_count(const int* __restrict__ dst, int* __restrict__ gcnt, int E) {
    __shared__ int c[NBUCK];
    int t = threadIdx.x;
    if (t < NBUCK) c[t] = 0;
    __syncthreads();
    int chunk = (E + NCB - 1) / NCB;
    int start = blockIdx.x * chunk;
    int end = min(E, start + chunk);
    #pragma unroll 4
    for (int e = start + t; e < end; e += 256)
        atomicAdd(&c[dst[e] >> BSH], 1);
    __syncthreads();
    if (t < NBUCK) gcnt[t * NCB + blockIdx.x] = c[t];
}

// ---------------- scan: exclusive prefix over 100352 counts ----------------
__global__ __launch_bounds__(1024) void k_scan(int* gcnt) {
    __shared__ int part[1024];
    int t = threadIdx.x;
    const int PER = GCNT_TOT / 1024;   // 98
    int base = t * PER;
    int s = 0;
    for (int i = 0; i < PER; i++) s += gcnt[base + i];
    part[t] = s;
    __syncthreads();
    for (int off = 1; off < 1024; off <<= 1) {
        int a = part[t];
        int b = (t >= off) ? part[t - off] : 0;
        __syncthreads();
        part[t] = a + b;
        __syncthreads();
    }
    int ex = (t == 0) ? 0 : part[t - 1];
    for (int i = 0; i < PER; i++) { int tmp = gcnt[base + i]; gcnt[base + i] = ex; ex += tmp; }
}

// ---------------- scatter: bucket edges, packed (dloc<<17)|src -------------
__global__ __launch_bounds__(256) void k_scatter(const int* __restrict__ src, const int* __restrict__ dst,
                                                 const int* __restrict__ gcnt,
                                                 unsigned int* __restrict__ bpk, int E) {
    __shared__ int off[NBUCK];
    int t = threadIdx.x;
    if (t < NBUCK) off[t] = gcnt[t * NCB + blockIdx.x];
    __syncthreads();
    int chunk = (E + NCB - 1) / NCB;
    int start = blockIdx.x * chunk;
    int end = min(E, start + chunk);
    for (int e = start + t; e < end; e += 256) {
        int s = src[e];
        int d = dst[e];
        int kb = d >> BSH;
        int pos = atomicAdd(&off[kb], 1);
        bpk[pos] = ((unsigned)(d & (BN - 1)) << 17) | (unsigned)s;
    }
}

// ---------------- deg histogram per bucket (exact) -> dinv plain store -----
__global__ __launch_bounds__(1024) void k_bdeg(const unsigned int* __restrict__ bpk, const int* __restrict__ gcnt,
                                               float* __restrict__ dinv, int E, int N) {
    __shared__ int hist[BN];
    int t = threadIdx.x;
    int k = blockIdx.x;
    if (t < BN) hist[t] = 0;
    __syncthreads();
    int bstart = gcnt[k * NCB];
    int bend = (k < NBUCK - 1) ? gcnt[(k + 1) * NCB] : E;
    #pragma unroll 4
    for (int e = bstart + t; e < bend; e += 1024)
        atomicAdd(&hist[bpk[e] >> 17], 1);
    __syncthreads();
    if (t < BN) {
        int node = (k << BSH) + t;
        if (node < N) dinv[node] = 1.0f / sqrtf(1.0f + (float)hist[t]);   // +1 self loop
    }
}

// ---------------- h1s = dinv * (x @ W1) ------------------------------------
// block = 256 = 16 nodes x 16 hidden; float4 LDS reads via transposed W
__global__ __launch_bounds__(256) void k_xw1(const float* __restrict__ x, const float* __restrict__ W1,
                                             const float* __restrict__ dinv,
                                             float* __restrict__ h1s, int N) {
    __shared__ float sWT[HID * NFEAT];   // transposed: [h][k]
    __shared__ float sx[16 * 132];
    int t = threadIdx.x;
    for (int i = t; i < HID * NFEAT; i += 256) {
        int h = i >> 7, k = i & 127;
        sWT[i] = W1[k * HID + h];
    }
    int local = t >> 4;
    int h     = t & 15;
    int n = blockIdx.x * 16 + local;
    if (n < N) {
        const float4* xr = (const float4*)(x + (size_t)n * NFEAT);
        float4 a = xr[h * 2];
        float4 b = xr[h * 2 + 1];
        float* sp = sx + local * 132 + h * 8;
        ((float4*)sp)[0] = a;
        ((float4*)sp)[1] = b;
    }
    __syncthreads();
    if (n >= N) return;
    const float4* xr4 = (const float4*)(sx + local * 132);
    const float4* wr4 = (const float4*)(sWT + (h << 7));
    float acc = 0.0f;
    #pragma unroll
    for (int k4 = 0; k4 < 32; k4++) {
        float4 a = xr4[k4];
        float4 b = wr4[k4];
        acc += a.x * b.x + a.y * b.y + a.z * b.z + a.w * b.w;
    }
    h1s[(size_t)n * HID + h] = acc * dinv[n];
}

// ---------------- agg1: bucketed LDS accumulation, 4 lanes/edge, U=4 -------
__global__ __launch_bounds__(512) void k_agg(const unsigned int* __restrict__ bpk, const int* __restrict__ gcnt,
                                             const float* __restrict__ h1s,
                                             float* __restrict__ agg1, int E, int N) {
    __shared__ float acc[BN * AST];      // 34816 B
    int t = threadIdx.x;
    int k = blockIdx.x >> 2, sp = blockIdx.x & (SPLITS_A - 1);
    int nbase = k << BSH;
    for (int i = t; i < BN * AST; i += 512) acc[i] = 0.0f;
    __syncthreads();
    if (sp == 0) {   // seed self-loop h1s[d]
        for (int i = t; i < BN * 4; i += 512) {
            int node = nbase + (i >> 2);
            if (node < N) {
                float4 v = ((const float4*)h1s)[(size_t)node * 4 + (i & 3)];
                float* a = &acc[(i >> 2) * AST + (i & 3) * 4];
                a[0] = v.x; a[1] = v.y; a[2] = v.z; a[3] = v.w;
            }
        }
    }
    __syncthreads();
    int bstart = gcnt[k * NCB];
    int bend = (k < NBUCK - 1) ? gcnt[(k + 1) * NCB] : E;
    int len = bend - bstart;
    int es = bstart + (int)((long long)len * sp / SPLITS_A);
    int ee = bstart + (int)((long long)len * (sp + 1) / SPLITS_A);
    int q = t & 3;          // quad within edge (4 floats each)
    int eo = t >> 2;        // edge slot 0..127
    int e = es + eo;
    for (; e + 384 < ee; e += 512) {
        unsigned w0 = bpk[e];
        unsigned w1 = bpk[e + 128];
        unsigned w2 = bpk[e + 256];
        unsigned w3 = bpk[e + 384];
        float4 v0 = ((const float4*)h1s)[(size_t)(w0 & 0x1FFFF) * 4 + q];
        float4 v1 = ((const float4*)h1s)[(size_t)(w1 & 0x1FFFF) * 4 + q];
        float4 v2 = ((const float4*)h1s)[(size_t)(w2 & 0x1FFFF) * 4 + q];
        float4 v3 = ((const float4*)h1s)[(size_t)(w3 & 0x1FFFF) * 4 + q];
        float* a0 = &acc[(w0 >> 17) * AST + (q << 2)];
        atomicAdd(a0 + 0, v0.x); atomicAdd(a0 + 1, v0.y); atomicAdd(a0 + 2, v0.z); atomicAdd(a0 + 3, v0.w);
        float* a1 = &acc[(w1 >> 17) * AST + (q << 2)];
        atomicAdd(a1 + 0, v1.x); atomicAdd(a1 + 1, v1.y); atomicAdd(a1 + 2, v1.z); atomicAdd(a1 + 3, v1.w);
        float* a2 = &acc[(w2 >> 17) * AST + (q << 2)];
        atomicAdd(a2 + 0, v2.x); atomicAdd(a2 + 1, v2.y); atomicAdd(a2 + 2, v2.z); atomicAdd(a2 + 3, v2.w);
        float* a3 = &acc[(w3 >> 17) * AST + (q << 2)];
        atomicAdd(a3 + 0, v3.x); atomicAdd(a3 + 1, v3.y); atomicAdd(a3 + 2, v3.z); atomicAdd(a3 + 3, v3.w);
    }
    for (; e < ee; e += 128) {
        unsigned w = bpk[e];
        float4 v = ((const float4*)h1s)[(size_t)(w & 0x1FFFF) * 4 + q];
        float* a = &acc[(w >> 17) * AST + (q << 2)];
        atomicAdd(a + 0, v.x); atomicAdd(a + 1, v.y); atomicAdd(a + 2, v.z); atomicAdd(a + 3, v.w);
    }
    __syncthreads();
    // flush: contiguous coalesced global atomics (splits combine); WRITE ~26MB
    for (int i = t; i < BN * 4; i += 512) {
        int node = nbase + (i >> 2);
        if (node < N) {
            float* a = &acc[(i >> 2) * AST + (i & 3) * 4];
            size_t g = (size_t)node * HID + (i & 3) * 4;
            atomicAdd(&agg1[g + 0], a[0]);
            atomicAdd(&agg1[g + 1], a[1]);
            atomicAdd(&agg1[g + 2], a[2]);
            atomicAdd(&agg1[g + 3], a[3]);
        }
    }
}

// ---------------- PReLU(dinv*agg1 + b1) @ W2 ; t2s = dinv*t2 ---------------
__global__ __launch_bounds__(256) void k_mid(const float* __restrict__ agg1, const float* __restrict__ b1,
                                             const float* __restrict__ prelu_a, const float* __restrict__ W2,
                                             const float* __restrict__ dinv,
                                             float* __restrict__ t2s, int N) {
    int n = blockIdx.x * 256 + threadIdx.x;
    if (n >= N) return;
    float a = prelu_a[0];
    float di = dinv[n];
    float v[HID];
    const float4* p = (const float4*)(agg1 + (size_t)n * HID);
    #pragma unroll
    for (int i = 0; i < 4; i++) {
        float4 qq = p[i];
        v[4 * i + 0] = qq.x; v[4 * i + 1] = qq.y; v[4 * i + 2] = qq.z; v[4 * i + 3] = qq.w;
    }
    float o0 = 0.0f, o1 = 0.0f;
    #pragma unroll
    for (int i = 0; i < HID; i++) {
        float tv = di * v[i] + b1[i];
        tv = (tv >= 0.0f) ? tv : a * tv;
        o0 += tv * W2[i * 2 + 0];
        o1 += tv * W2[i * 2 + 1];
    }
    t2s[n * 2 + 0] = di * o0;
    t2s[n * 2 + 1] = di * o1;
}

// ---------------- edge pass 2 + pool: bucketed, per-block partials ---------
__global__ __launch_bounds__(1024) void k_e2pool(const unsigned int* __restrict__ bpk, const int* __restrict__ gcnt,
                                                 const float* __restrict__ dinv, const float* __restrict__ t2s,
                                                 const int* __restrict__ batch,
                                                 float* __restrict__ partials, int E, int N) {
    __shared__ float acc2[BN * E2ST];    // 6 KB
    __shared__ float pg[PSTRIDE];
    int t = threadIdx.x;
    int k = blockIdx.x >> 2, sp = blockIdx.x & (SPLITS_E - 1);
    int nbase = k << BSH;
    for (int i = t; i < BN * E2ST; i += 1024) acc2[i] = 0.0f;
    if (t < PSTRIDE) pg[t] = 0.0f;
    __syncthreads();
    if (sp == 0) {   // seed self-loop t2s[d]; exactly 1024 items
        int node = nbase + (t >> 1);
        if (node < N) acc2[(t >> 1) * E2ST + (t & 1)] = t2s[(size_t)node * 2 + (t & 1)];
    }
    __syncthreads();
    int bstart = gcnt[k * NCB];
    int bend = (k < NBUCK - 1) ? gcnt[(k + 1) * NCB] : E;
    int len = bend - bstart;
    int es = bstart + (int)((long long)len * sp / SPLITS_E);
    int ee = bstart + (int)((long long)len * (sp + 1) / SPLITS_E);
    int e = es + t;
    for (; e + 3072 < ee; e += 4096) {
        unsigned w0 = bpk[e];
        unsigned w1 = bpk[e + 1024];
        unsigned w2 = bpk[e + 2048];
        unsigned w3 = bpk[e + 3072];
        float2 f0 = ((const float2*)t2s)[w0 & 0x1FFFF];
        float2 f1 = ((const float2*)t2s)[w1 & 0x1FFFF];
        float2 f2 = ((const float2*)t2s)[w2 & 0x1FFFF];
        float2 f3 = ((const float2*)t2s)[w3 & 0x1FFFF];
        atomicAdd(&acc2[(w0 >> 17) * E2ST + 0], f0.x); atomicAdd(&acc2[(w0 >> 17) * E2ST + 1], f0.y);
        atomicAdd(&acc2[(w1 >> 17) * E2ST + 0], f1.x); atomicAdd(&acc2[(w1 >> 17) * E2ST + 1], f1.y);
        atomicAdd(&acc2[(w2 >> 17) * E2ST + 0], f2.x); atomicAdd(&acc2[(w2 >> 17) * E2ST + 1], f2.y);
        atomicAdd(&acc2[(w3 >> 17) * E2ST + 0], f3.x); atomicAdd(&acc2[(w3 >> 17) * E2ST + 1], f3.y);
    }
    for (; e < ee; e += 1024) {
        unsigned w = bpk[e];
        float2 f = ((const float2*)t2s)[w & 0x1FFFF];
        atomicAdd(&acc2[(w >> 17) * E2ST + 0], f.x);
        atomicAdd(&acc2[(w >> 17) * E2ST + 1], f.y);
    }
    __syncthreads();
    if (t < BN) {
        int node = nbase + t;
        if (node < N) {
            float dd = dinv[node];
            int g = batch[node];
            atomicAdd(&pg[g * 2 + 0], dd * acc2[t * E2ST + 0]);
            atomicAdd(&pg[g * 2 + 1], dd * acc2[t * E2ST + 1]);
            if (sp == 0) atomicAdd(&pg[128 + g], 1.0f);
        }
    }
    __syncthreads();
    if (t < PSTRIDE) partials[(size_t)blockIdx.x * PSTRIDE + t] = pg[t];
}

// ---------------- final: reduce partials, add bias, divide -----------------
__global__ __launch_bounds__(256) void k_final(const float* __restrict__ partials,
                                               const float* __restrict__ b2, float* __restrict__ out) {
    __shared__ float fs[PSTRIDE];
    int t = threadIdx.x;
    if (t < PSTRIDE) {
        float s = 0.0f;
        for (int r = 0; r < NPART; r++) s += partials[(size_t)r * PSTRIDE + t];
        fs[t] = s;
    }
    __syncthreads();
    if (t < NGRAPH * NOUT) {
        int g = t >> 1, c = t & 1;
        float cnt = fs[128 + g];
        out[t] = (fs[t] + cnt * b2[c]) / fmaxf(cnt, 1.0f);
    }
}

extern "C" void kernel_launch(void* const* d_in, const int* in_sizes, int n_in,
                              void* d_out, int out_size, void* d_ws, size_t ws_size,
                              hipStream_t stream) {
    const float* x       = (const float*)d_in[0];
    const float* W1      = (const float*)d_in[1];
    const float* b1      = (const float*)d_in[2];
    const float* prelu_a = (const float*)d_in[3];
    const float* W2      = (const float*)d_in[4];
    const float* b2      = (const float*)d_in[5];
    const int*   ei      = (const int*)d_in[6];
    const int*   batch   = (const int*)d_in[7];

    const int N = in_sizes[7];          // 100000
    const int E = in_sizes[6] / 2;      // 6400000
    const int* src = ei;
    const int* dst = ei + E;

    // workspace layout (4-byte units), ~41 MB total
    float* ws   = (float*)d_ws;
    float* dinv = ws;                                     // N
    float* h1s  = dinv + N;                               // 16N
    float* agg1 = h1s + (size_t)N * HID;                  // 16N
    float* t2s  = agg1 + (size_t)N * HID;                 // 2N
    int*   gcnt = (int*)(t2s + (size_t)N * NOUT);         // 100352
    unsigned int* bpk = (unsigned int*)(gcnt + GCNT_TOT); // E
    float* partials = (float*)(bpk + E);                  // NPART*PSTRIDE

    float* out = (float*)d_out;

    k_init<<<(N * HID + 255) / 256, 256, 0, stream>>>(agg1, N);
    k_count<<<NCB, 256, 0, stream>>>(dst, gcnt, E);
    k_scan<<<1, 1024, 0, stream>>>(gcnt);
    k_scatter<<<NCB, 256, 0, stream>>>(src, dst, gcnt, bpk, E);
    k_bdeg<<<NBUCK, 1024, 0, stream>>>(bpk, gcnt, dinv, E, N);
    k_xw1<<<(N + 15) / 16, 256, 0, stream>>>(x, W1, dinv, h1s, N);
    k_agg<<<NBUCK * SPLITS_A, 512, 0, stream>>>(bpk, gcnt, h1s, agg1, E, N);
    k_mid<<<(N + 255) / 256, 256, 0, stream>>>(agg1, b1, prelu_a, W2, dinv, t2s, N);
    k_e2pool<<<NBUCK * SPLITS_E, 1024, 0, stream>>>(bpk, gcnt, dinv, t2s, batch, partials, E, N);
    k_final<<<1, 256, 0, stream>>>(partials, b2, out);
}

// Round 5
// 682.083 us; speedup vs baseline: 1.6853x; 1.6853x over previous
//
#include <hip/hip_runtime.h>

#define NFEAT 128
#define HID 16
#define NOUT 2
#define NGRAPH 64

#define BSH 8                      // bucket shift: 256 nodes/bucket
#define BN 256                     // nodes per bucket
#define NBUCK 391                  // ceil(100000/256)
#define NCB 256                    // count/scatter chunk blocks
#define GCNT_TOT (NBUCK * NCB)     // 100096
#define SCAP 18176                 // staged edges per bucket (71 KB); mean 16368, +14 sigma
#define OVR 8                      // register overflow slots/thread (covers +78 sigma)
#define PSTRIDE 192                // 128 graph sums + 64 counts
#define GB2 782                    // gather2 blocks = ceil(100000/128)

// ---------------- count: per-(bucket, chunk) histogram ---------------------
__global__ __launch_bounds__(256) void k_count(const int* __restrict__ dst, int* __restrict__ gcnt, int E) {
    __shared__ int c[NBUCK];
    int t = threadIdx.x;
    for (int i = t; i < NBUCK; i += 256) c[i] = 0;
    __syncthreads();
    int chunk = (E + NCB - 1) / NCB;
    int start = blockIdx.x * chunk;
    int end = min(E, start + chunk);
    for (int e = start + t; e < end; e += 256)
        atomicAdd(&c[dst[e] >> BSH], 1);
    __syncthreads();
    for (int i = t; i < NBUCK; i += 256) gcnt[i * NCB + blockIdx.x] = c[i];
}

// ---------------- scan: exclusive prefix over 100096 counts ----------------
__global__ __launch_bounds__(1024) void k_scan(int* gcnt) {
    __shared__ int part[1024];
    int t = threadIdx.x;
    const int PER = (GCNT_TOT + 1023) / 1024;   // 98
    int base = t * PER;
    int s = 0;
    for (int i = 0; i < PER; i++) { int idx = base + i; if (idx < GCNT_TOT) s += gcnt[idx]; }
    part[t] = s;
    __syncthreads();
    for (int off = 1; off < 1024; off <<= 1) {
        int a = part[t];
        int b = (t >= off) ? part[t - off] : 0;
        __syncthreads();
        part[t] = a + b;
        __syncthreads();
    }
    int ex = (t == 0) ? 0 : part[t - 1];
    for (int i = 0; i < PER; i++) {
        int idx = base + i;
        if (idx < GCNT_TOT) { int tmp = gcnt[idx]; gcnt[idx] = ex; ex += tmp; }
    }
}

// ---------------- scatter: bucket edges, packed (dloc<<17)|src -------------
__global__ __launch_bounds__(256) void k_scatter(const int* __restrict__ src, const int* __restrict__ dst,
                                                 const int* __restrict__ gcnt,
                                                 unsigned int* __restrict__ bpk, int E) {
    __shared__ int off[NBUCK];
    int t = threadIdx.x;
    for (int i = t; i < NBUCK; i += 256) off[i] = gcnt[i * NCB + blockIdx.x];
    __syncthreads();
    int chunk = (E + NCB - 1) / NCB;
    int start = blockIdx.x * chunk;
    int end = min(E, start + chunk);
    for (int e = start + t; e < end; e += 256) {
        int s = src[e];
        int d = dst[e];
        int kb = d >> BSH;
        int pos = atomicAdd(&off[kb], 1);
        bpk[pos] = ((unsigned)(d & (BN - 1)) << 17) | (unsigned)s;
    }
}

// ---------------- sort: per-bucket counting sort (in place) -> CSR ---------
// stages bucket edges in LDS; hist -> rowptr + dinv; rank-scatter src in place
__global__ __launch_bounds__(1024) void k_sort(unsigned int* __restrict__ bpk, const int* __restrict__ gcnt,
                                               int* __restrict__ rowptr, float* __restrict__ dinv, int E, int N) {
    __shared__ unsigned int stage[SCAP];     // 71 KB
    __shared__ int hist[BN], excl[BN], cur[BN];
    int t = threadIdx.x;
    int k = blockIdx.x;
    int bstart = gcnt[k * NCB];
    int bend = (k < NBUCK - 1) ? gcnt[(k + 1) * NCB] : E;
    int len = bend - bstart;
    int nst = min(len, SCAP);
    if (t < BN) hist[t] = 0;
    // stage (coalesced read); overflow beyond SCAP into registers (read-before-write safety)
    for (int j = t; j < nst; j += 1024) stage[j] = bpk[bstart + j];
    unsigned int ov[OVR];
    int nov = 0;
    for (int j = SCAP + t; j < len; j += 1024)
        if (nov < OVR) ov[nov++] = bpk[bstart + j];
    __syncthreads();
    // pass 1: histogram
    for (int j = t; j < nst; j += 1024) atomicAdd(&hist[stage[j] >> 17], 1);
    for (int i = 0; i < nov; i++) atomicAdd(&hist[ov[i] >> 17], 1);
    __syncthreads();
    // exclusive scan over 256 bins (Hillis-Steele, full-block barriers)
    if (t < BN) excl[t] = hist[t];
    __syncthreads();
    for (int off = 1; off < BN; off <<= 1) {
        int v = 0;
        if (t < BN && t >= off) v = excl[t - off];
        __syncthreads();
        if (t < BN && t >= off) excl[t] += v;
        __syncthreads();
    }
    if (t < BN) {
        int ex = excl[t] - hist[t];
        cur[t] = ex;
        int node = (k << BSH) + t;
        rowptr[node] = bstart + ex;                        // covers rowptr[N] too
        if (node < N) dinv[node] = 1.0f / sqrtf(1.0f + (float)hist[t]);
    }
    __syncthreads();
    // pass 2: rank + in-place scatter (store plain src)
    for (int j = t; j < nst; j += 1024) {
        unsigned int w = stage[j];
        int r = atomicAdd(&cur[w >> 17], 1);
        bpk[bstart + r] = w & 0x1FFFF;
    }
    for (int i = 0; i < nov; i++) {
        unsigned int w = ov[i];
        int r = atomicAdd(&cur[w >> 17], 1);
        bpk[bstart + r] = w & 0x1FFFF;
    }
}

// ---------------- h1s = dinv * (x @ W1) ------------------------------------
__global__ __launch_bounds__(256) void k_xw1(const float* __restrict__ x, const float* __restrict__ W1,
                                             const float* __restrict__ dinv,
                                             float* __restrict__ h1s, int N) {
    __shared__ float sWT[HID * NFEAT];   // transposed: [h][k]
    __shared__ float sx[16 * 132];
    int t = threadIdx.x;
    for (int i = t; i < HID * NFEAT; i += 256) {
        int h = i >> 7, kk = i & 127;
        sWT[i] = W1[kk * HID + h];
    }
    int local = t >> 4;
    int h     = t & 15;
    int n = blockIdx.x * 16 + local;
    if (n < N) {
        const float4* xr = (const float4*)(x + (size_t)n * NFEAT);
        float4 a = xr[h * 2];
        float4 b = xr[h * 2 + 1];
        float* sp = sx + local * 132 + h * 8;
        ((float4*)sp)[0] = a;
        ((float4*)sp)[1] = b;
    }
    __syncthreads();
    if (n >= N) return;
    const float4* xr4 = (const float4*)(sx + local * 132);
    const float4* wr4 = (const float4*)(sWT + (h << 7));
    float acc = 0.0f;
    #pragma unroll
    for (int k4 = 0; k4 < 32; k4++) {
        float4 a = xr4[k4];
        float4 b = wr4[k4];
        acc += a.x * b.x + a.y * b.y + a.z * b.z + a.w * b.w;
    }
    h1s[(size_t)n * HID + h] = acc * dinv[n];
}

__device__ __forceinline__ void add4(float4& a, const float4 b) {
    a.x += b.x; a.y += b.y; a.z += b.z; a.w += b.w;
}

// ---------------- gather1: CSR register accumulation -> PReLU -> W2 -> t2s --
// 4 lanes per node (q = quad of 4 features); no atomics, no LDS
__global__ __launch_bounds__(256) void k_gather1(const int* __restrict__ esrc, const int* __restrict__ rowptr,
                                                 const float* __restrict__ h1s, const float* __restrict__ dinv,
                                                 const float* __restrict__ b1, const float* __restrict__ prelu_a,
                                                 const float* __restrict__ W2,
                                                 float* __restrict__ t2s, int N) {
    int t = threadIdx.x;
    int n = blockIdx.x * 64 + (t >> 2);
    int q = t & 3;
    if (n >= N) return;
    const float4* h4 = (const float4*)h1s;
    int r0 = rowptr[n];
    int r1 = rowptr[n + 1];
    float4 acc = h4[(size_t)n * 4 + q];        // self-loop seed
    int i = r0;
    for (; i + 4 <= r1; i += 4) {
        int s0 = esrc[i], s1 = esrc[i + 1], s2 = esrc[i + 2], s3 = esrc[i + 3];
        float4 v0 = h4[(size_t)s0 * 4 + q];
        float4 v1 = h4[(size_t)s1 * 4 + q];
        float4 v2 = h4[(size_t)s2 * 4 + q];
        float4 v3 = h4[(size_t)s3 * 4 + q];
        add4(acc, v0); add4(acc, v1); add4(acc, v2); add4(acc, v3);
    }
    for (; i < r1; i++) add4(acc, h4[(size_t)esrc[i] * 4 + q]);

    float di = dinv[n];
    float a = prelu_a[0];
    float4 bb = ((const float4*)b1)[q];
    float tv0 = di * acc.x + bb.x;
    float tv1 = di * acc.y + bb.y;
    float tv2 = di * acc.z + bb.z;
    float tv3 = di * acc.w + bb.w;
    tv0 = (tv0 >= 0.0f) ? tv0 : a * tv0;
    tv1 = (tv1 >= 0.0f) ? tv1 : a * tv1;
    tv2 = (tv2 >= 0.0f) ? tv2 : a * tv2;
    tv3 = (tv3 >= 0.0f) ? tv3 : a * tv3;
    int rb = q * 4;
    float o0 = tv0 * W2[(rb + 0) * 2] + tv1 * W2[(rb + 1) * 2] + tv2 * W2[(rb + 2) * 2] + tv3 * W2[(rb + 3) * 2];
    float o1 = tv0 * W2[(rb + 0) * 2 + 1] + tv1 * W2[(rb + 1) * 2 + 1] + tv2 * W2[(rb + 2) * 2 + 1] + tv3 * W2[(rb + 3) * 2 + 1];
    o0 += __shfl_xor(o0, 1); o0 += __shfl_xor(o0, 2);
    o1 += __shfl_xor(o1, 1); o1 += __shfl_xor(o1, 2);
    if (q == 0) {
        float2 r = make_float2(di * o0, di * o1);
        *(float2*)(t2s + (size_t)n * 2) = r;
    }
}

// ---------------- gather2 + pool: CSR sum of t2s -> per-graph bins ---------
// 2 lanes per node (c = output component)
__global__ __launch_bounds__(256) void k_gather2(const int* __restrict__ esrc, const int* __restrict__ rowptr,
                                                 const float* __restrict__ t2s, const float* __restrict__ dinv,
                                                 const int* __restrict__ batch,
                                                 float* __restrict__ partials, int N) {
    __shared__ float pg[PSTRIDE];
    int t = threadIdx.x;
    if (t < PSTRIDE) pg[t] = 0.0f;
    __syncthreads();
    int n = blockIdx.x * 128 + (t >> 1);
    int c = t & 1;
    if (n < N) {
        int r0 = rowptr[n];
        int r1 = rowptr[n + 1];
        float val = t2s[(size_t)n * 2 + c];    // self-loop
        int i = r0;
        for (; i + 4 <= r1; i += 4) {
            int s0 = esrc[i], s1 = esrc[i + 1], s2 = esrc[i + 2], s3 = esrc[i + 3];
            float v0 = t2s[(size_t)s0 * 2 + c];
            float v1 = t2s[(size_t)s1 * 2 + c];
            float v2 = t2s[(size_t)s2 * 2 + c];
            float v3 = t2s[(size_t)s3 * 2 + c];
            val += (v0 + v1) + (v2 + v3);
        }
        for (; i < r1; i++) val += t2s[(size_t)esrc[i] * 2 + c];
        float dd = dinv[n];
        int g = batch[n];
        atomicAdd(&pg[g * 2 + c], dd * val);
        if (c == 0) atomicAdd(&pg[128 + g], 1.0f);
    }
    __syncthreads();
    if (t < PSTRIDE) partials[(size_t)blockIdx.x * PSTRIDE + t] = pg[t];
}

// ---------------- final: reduce partials, add bias, divide -----------------
__global__ __launch_bounds__(256) void k_final(const float* __restrict__ partials,
                                               const float* __restrict__ b2, float* __restrict__ out) {
    __shared__ float fs[PSTRIDE];
    int t = threadIdx.x;
    if (t < PSTRIDE) {
        float s0 = 0.0f, s1 = 0.0f, s2 = 0.0f, s3 = 0.0f;
        int r = 0;
        for (; r + 4 <= GB2; r += 4) {
            s0 += partials[(size_t)r * PSTRIDE + t];
            s1 += partials[(size_t)(r + 1) * PSTRIDE + t];
            s2 += partials[(size_t)(r + 2) * PSTRIDE + t];
            s3 += partials[(size_t)(r + 3) * PSTRIDE + t];
        }
        for (; r < GB2; r++) s0 += partials[(size_t)r * PSTRIDE + t];
        fs[t] = (s0 + s1) + (s2 + s3);
    }
    __syncthreads();
    if (t < NGRAPH * NOUT) {
        int g = t >> 1, c = t & 1;
        float cnt = fs[128 + g];
        out[t] = (fs[t] + cnt * b2[c]) / fmaxf(cnt, 1.0f);
    }
}

extern "C" void kernel_launch(void* const* d_in, const int* in_sizes, int n_in,
                              void* d_out, int out_size, void* d_ws, size_t ws_size,
                              hipStream_t stream) {
    const float* x       = (const float*)d_in[0];
    const float* W1      = (const float*)d_in[1];
    const float* b1      = (const float*)d_in[2];
    const float* prelu_a = (const float*)d_in[3];
    const float* W2      = (const float*)d_in[4];
    const float* b2      = (const float*)d_in[5];
    const int*   ei      = (const int*)d_in[6];
    const int*   batch   = (const int*)d_in[7];

    const int N = in_sizes[7];          // 100000
    const int E = in_sizes[6] / 2;      // 6400000
    const int* src = ei;
    const int* dst = ei + E;

    // workspace layout (4-byte units), ~35 MB total
    float* ws     = (float*)d_ws;
    float* dinv   = ws;                                        // 100352
    float* h1s    = dinv + 100352;                             // 16N = 1.6M
    float* t2s    = h1s + (size_t)N * HID;                     // 2N
    int*   rowptr = (int*)(t2s + (size_t)N * NOUT);            // 100352 (>= NBUCK*BN+1)
    int*   gcnt   = rowptr + 100352;                           // GCNT_TOT
    unsigned int* bpk = (unsigned int*)(gcnt + GCNT_TOT);      // E (becomes esrc in place)
    float* partials = (float*)(bpk + E);                       // GB2*PSTRIDE

    float* out = (float*)d_out;

    k_count<<<NCB, 256, 0, stream>>>(dst, gcnt, E);
    k_scan<<<1, 1024, 0, stream>>>(gcnt);
    k_scatter<<<NCB, 256, 0, stream>>>(src, dst, gcnt, bpk, E);
    k_sort<<<NBUCK, 1024, 0, stream>>>(bpk, gcnt, rowptr, dinv, E, N);
    k_xw1<<<(N + 15) / 16, 256, 0, stream>>>(x, W1, dinv, h1s, N);
    k_gather1<<<(N + 63) / 64, 256, 0, stream>>>((const int*)bpk, rowptr, h1s, dinv, b1, prelu_a, W2, t2s, N);
    k_gather2<<<GB2, 256, 0, stream>>>((const int*)bpk, rowptr, t2s, dinv, batch, partials, N);
    k_final<<<1, 256, 0, stream>>>(partials, b2, out);
}

// Round 6
// 515.547 us; speedup vs baseline: 2.2296x; 1.3230x over previous
//
#include <hip/hip_runtime.h>

#define NFEAT 128
#define HID 16
#define NOUT 2
#define NGRAPH 64

#define BSH 8                      // bucket shift: 256 nodes/bucket
#define BN 256                     // nodes per bucket
#define NBUCK 391                  // ceil(100000/256)
#define NCB 256                    // count/scatter chunk blocks
#define GCNT_TOT (NBUCK * NCB)     // 100096
#define SCAN_NB 98                 // scan blocks: 98*1024 >= GCNT_TOT
#define SCAP 18176                 // staged edges per bucket (71 KB)
#define OVR 8                      // register overflow slots/thread
#define PSTRIDE 192                // 128 graph sums + 64 counts
#define GB2 782                    // gather2 blocks = ceil(100000/128)

// ---------------- count: per-(bucket, chunk) histogram ---------------------
__global__ __launch_bounds__(256) void k_count(const int* __restrict__ dst, int* __restrict__ gcnt, int E) {
    __shared__ int c[NBUCK];
    int t = threadIdx.x;
    for (int i = t; i < NBUCK; i += 256) c[i] = 0;
    __syncthreads();
    int chunk = (E + NCB - 1) / NCB;
    int start = blockIdx.x * chunk;
    int end = min(E, start + chunk);
    for (int e = start + t; e < end; e += 256)
        atomicAdd(&c[dst[e] >> BSH], 1);
    __syncthreads();
    for (int i = t; i < NBUCK; i += 256) gcnt[i * NCB + blockIdx.x] = c[i];
}

// ---------------- scan stage 1: block-local exclusive scan + block sums ----
__global__ __launch_bounds__(1024) void k_scan1(int* __restrict__ gcnt, int* __restrict__ bsum) {
    __shared__ int sh[1024];
    int t = threadIdx.x;
    int idx = blockIdx.x * 1024 + t;
    int v = (idx < GCNT_TOT) ? gcnt[idx] : 0;
    sh[t] = v;
    __syncthreads();
    for (int off = 1; off < 1024; off <<= 1) {
        int a = sh[t];
        int b = (t >= off) ? sh[t - off] : 0;
        __syncthreads();
        sh[t] = a + b;
        __syncthreads();
    }
    if (idx < GCNT_TOT) gcnt[idx] = sh[t] - v;     // exclusive within block
    if (t == 1023) bsum[blockIdx.x] = sh[1023];
}

// ---------------- scan stage 2: scan the 98 block sums ---------------------
__global__ __launch_bounds__(128) void k_scan2(int* __restrict__ bsum) {
    __shared__ int sh[128];
    int t = threadIdx.x;
    int v = (t < SCAN_NB) ? bsum[t] : 0;
    sh[t] = v;
    __syncthreads();
    for (int off = 1; off < 128; off <<= 1) {
        int a = sh[t];
        int b = (t >= off) ? sh[t - off] : 0;
        __syncthreads();
        sh[t] = a + b;
        __syncthreads();
    }
    if (t < SCAN_NB) bsum[t] = sh[t] - v;          // exclusive
}

// ---------------- scan stage 3: add block offsets --------------------------
__global__ __launch_bounds__(1024) void k_scan3(int* __restrict__ gcnt, const int* __restrict__ bsum) {
    int idx = blockIdx.x * 1024 + threadIdx.x;
    if (idx < GCNT_TOT) gcnt[idx] += bsum[blockIdx.x];
}

// ---------------- scatter: bucket edges, packed (dloc<<17)|src -------------
__global__ __launch_bounds__(256) void k_scatter(const int* __restrict__ src, const int* __restrict__ dst,
                                                 const int* __restrict__ gcnt,
                                                 unsigned int* __restrict__ bpk, int E) {
    __shared__ int off[NBUCK];
    int t = threadIdx.x;
    for (int i = t; i < NBUCK; i += 256) off[i] = gcnt[i * NCB + blockIdx.x];
    __syncthreads();
    int chunk = (E + NCB - 1) / NCB;
    int start = blockIdx.x * chunk;
    int end = min(E, start + chunk);
    for (int e = start + t; e < end; e += 256) {
        int s = src[e];
        int d = dst[e];
        int kb = d >> BSH;
        int pos = atomicAdd(&off[kb], 1);
        bpk[pos] = ((unsigned)(d & (BN - 1)) << 17) | (unsigned)s;
    }
}

// ---------------- sort: per-bucket counting sort (in place) -> CSR ---------
__global__ __launch_bounds__(1024) void k_sort(unsigned int* __restrict__ bpk, const int* __restrict__ gcnt,
                                               int* __restrict__ rowptr, float* __restrict__ dinv, int E, int N) {
    __shared__ unsigned int stage[SCAP];     // 71 KB
    __shared__ int hist[BN], excl[BN], cur[BN];
    int t = threadIdx.x;
    int k = blockIdx.x;
    int bstart = gcnt[k * NCB];
    int bend = (k < NBUCK - 1) ? gcnt[(k + 1) * NCB] : E;
    int len = bend - bstart;
    int nst = min(len, SCAP);
    if (t < BN) hist[t] = 0;
    for (int j = t; j < nst; j += 1024) stage[j] = bpk[bstart + j];
    unsigned int ov[OVR];
    int nov = 0;
    for (int j = SCAP + t; j < len; j += 1024)
        if (nov < OVR) ov[nov++] = bpk[bstart + j];
    __syncthreads();
    for (int j = t; j < nst; j += 1024) atomicAdd(&hist[stage[j] >> 17], 1);
    for (int i = 0; i < nov; i++) atomicAdd(&hist[ov[i] >> 17], 1);
    __syncthreads();
    if (t < BN) excl[t] = hist[t];
    __syncthreads();
    for (int off = 1; off < BN; off <<= 1) {
        int v = 0;
        if (t < BN && t >= off) v = excl[t - off];
        __syncthreads();
        if (t < BN && t >= off) excl[t] += v;
        __syncthreads();
    }
    if (t < BN) {
        int ex = excl[t] - hist[t];
        cur[t] = ex;
        int node = (k << BSH) + t;
        rowptr[node] = bstart + ex;
        if (node < N) dinv[node] = 1.0f / sqrtf(1.0f + (float)hist[t]);
    }
    __syncthreads();
    for (int j = t; j < nst; j += 1024) {
        unsigned int w = stage[j];
        int r = atomicAdd(&cur[w >> 17], 1);
        bpk[bstart + r] = w & 0x1FFFF;
    }
    for (int i = 0; i < nov; i++) {
        unsigned int w = ov[i];
        int r = atomicAdd(&cur[w >> 17], 1);
        bpk[bstart + r] = w & 0x1FFFF;
    }
}

// ---------------- h1s = dinv * (x @ W1) ------------------------------------
__global__ __launch_bounds__(256) void k_xw1(const float* __restrict__ x, const float* __restrict__ W1,
                                             const float* __restrict__ dinv,
                                             float* __restrict__ h1s, int N) {
    __shared__ float sWT[HID * NFEAT];   // transposed: [h][k]
    __shared__ float sx[16 * 132];
    int t = threadIdx.x;
    for (int i = t; i < HID * NFEAT; i += 256) {
        int h = i >> 7, kk = i & 127;
        sWT[i] = W1[kk * HID + h];
    }
    int local = t >> 4;
    int h     = t & 15;
    int n = blockIdx.x * 16 + local;
    if (n < N) {
        const float4* xr = (const float4*)(x + (size_t)n * NFEAT);
        float4 a = xr[h * 2];
        float4 b = xr[h * 2 + 1];
        float* sp = sx + local * 132 + h * 8;
        ((float4*)sp)[0] = a;
        ((float4*)sp)[1] = b;
    }
    __syncthreads();
    if (n >= N) return;
    const float4* xr4 = (const float4*)(sx + local * 132);
    const float4* wr4 = (const float4*)(sWT + (h << 7));
    float acc = 0.0f;
    #pragma unroll
    for (int k4 = 0; k4 < 32; k4++) {
        float4 a = xr4[k4];
        float4 b = wr4[k4];
        acc += a.x * b.x + a.y * b.y + a.z * b.z + a.w * b.w;
    }
    h1s[(size_t)n * HID + h] = acc * dinv[n];
}

__device__ __forceinline__ void add4(float4& a, const float4 b) {
    a.x += b.x; a.y += b.y; a.z += b.z; a.w += b.w;
}

// ---------------- gather1: CSR register accumulation -> PReLU -> W2 -> t2s --
__global__ __launch_bounds__(256) void k_gather1(const int* __restrict__ esrc, const int* __restrict__ rowptr,
                                                 const float* __restrict__ h1s, const float* __restrict__ dinv,
                                                 const float* __restrict__ b1, const float* __restrict__ prelu_a,
                                                 const float* __restrict__ W2,
                                                 float* __restrict__ t2s, int N) {
    int t = threadIdx.x;
    int n = blockIdx.x * 64 + (t >> 2);
    int q = t & 3;
    if (n >= N) return;
    const float4* h4 = (const float4*)h1s;
    int r0 = rowptr[n];
    int r1 = rowptr[n + 1];
    float4 acc = h4[(size_t)n * 4 + q];        // self-loop seed
    int i = r0;
    for (; i + 4 <= r1; i += 4) {
        int s0 = esrc[i], s1 = esrc[i + 1], s2 = esrc[i + 2], s3 = esrc[i + 3];
        float4 v0 = h4[(size_t)s0 * 4 + q];
        float4 v1 = h4[(size_t)s1 * 4 + q];
        float4 v2 = h4[(size_t)s2 * 4 + q];
        float4 v3 = h4[(size_t)s3 * 4 + q];
        add4(acc, v0); add4(acc, v1); add4(acc, v2); add4(acc, v3);
    }
    for (; i < r1; i++) add4(acc, h4[(size_t)esrc[i] * 4 + q]);

    float di = dinv[n];
    float a = prelu_a[0];
    float4 bb = ((const float4*)b1)[q];
    float tv0 = di * acc.x + bb.x;
    float tv1 = di * acc.y + bb.y;
    float tv2 = di * acc.z + bb.z;
    float tv3 = di * acc.w + bb.w;
    tv0 = (tv0 >= 0.0f) ? tv0 : a * tv0;
    tv1 = (tv1 >= 0.0f) ? tv1 : a * tv1;
    tv2 = (tv2 >= 0.0f) ? tv2 : a * tv2;
    tv3 = (tv3 >= 0.0f) ? tv3 : a * tv3;
    int rb = q * 4;
    float o0 = tv0 * W2[(rb + 0) * 2] + tv1 * W2[(rb + 1) * 2] + tv2 * W2[(rb + 2) * 2] + tv3 * W2[(rb + 3) * 2];
    float o1 = tv0 * W2[(rb + 0) * 2 + 1] + tv1 * W2[(rb + 1) * 2 + 1] + tv2 * W2[(rb + 2) * 2 + 1] + tv3 * W2[(rb + 3) * 2 + 1];
    o0 += __shfl_xor(o0, 1); o0 += __shfl_xor(o0, 2);
    o1 += __shfl_xor(o1, 1); o1 += __shfl_xor(o1, 2);
    if (q == 0) {
        float2 r = make_float2(di * o0, di * o1);
        *(float2*)(t2s + (size_t)n * 2) = r;
    }
}

// ---------------- gather2 + pool: CSR sum of t2s -> per-graph bins ---------
__global__ __launch_bounds__(256) void k_gather2(const int* __restrict__ esrc, const int* __restrict__ rowptr,
                                                 const float* __restrict__ t2s, const float* __restrict__ dinv,
                                                 const int* __restrict__ batch,
                                                 float* __restrict__ partials, int N) {
    __shared__ float pg[PSTRIDE];
    int t = threadIdx.x;
    if (t < PSTRIDE) pg[t] = 0.0f;
    __syncthreads();
    int n = blockIdx.x * 128 + (t >> 1);
    int c = t & 1;
    if (n < N) {
        int r0 = rowptr[n];
        int r1 = rowptr[n + 1];
        float val = t2s[(size_t)n * 2 + c];    // self-loop
        int i = r0;
        for (; i + 4 <= r1; i += 4) {
            int s0 = esrc[i], s1 = esrc[i + 1], s2 = esrc[i + 2], s3 = esrc[i + 3];
            float v0 = t2s[(size_t)s0 * 2 + c];
            float v1 = t2s[(size_t)s1 * 2 + c];
            float v2 = t2s[(size_t)s2 * 2 + c];
            float v3 = t2s[(size_t)s3 * 2 + c];
            val += (v0 + v1) + (v2 + v3);
        }
        for (; i < r1; i++) val += t2s[(size_t)esrc[i] * 2 + c];
        float dd = dinv[n];
        int g = batch[n];
        atomicAdd(&pg[g * 2 + c], dd * val);
        if (c == 0) atomicAdd(&pg[128 + g], 1.0f);
    }
    __syncthreads();
    if (t < PSTRIDE) partials[(size_t)blockIdx.x * PSTRIDE + t] = pg[t];
}

// ---------------- final: reduce partials, add bias, divide -----------------
__global__ __launch_bounds__(256) void k_final(const float* __restrict__ partials,
                                               const float* __restrict__ b2, float* __restrict__ out) {
    __shared__ float fs[PSTRIDE];
    int t = threadIdx.x;
    if (t < PSTRIDE) {
        float s0 = 0.0f, s1 = 0.0f, s2 = 0.0f, s3 = 0.0f;
        int r = 0;
        for (; r + 4 <= GB2; r += 4) {
            s0 += partials[(size_t)r * PSTRIDE + t];
            s1 += partials[(size_t)(r + 1) * PSTRIDE + t];
            s2 += partials[(size_t)(r + 2) * PSTRIDE + t];
            s3 += partials[(size_t)(r + 3) * PSTRIDE + t];
        }
        for (; r < GB2; r++) s0 += partials[(size_t)r * PSTRIDE + t];
        fs[t] = (s0 + s1) + (s2 + s3);
    }
    __syncthreads();
    if (t < NGRAPH * NOUT) {
        int g = t >> 1, c = t & 1;
        float cnt = fs[128 + g];
        out[t] = (fs[t] + cnt * b2[c]) / fmaxf(cnt, 1.0f);
    }
}

extern "C" void kernel_launch(void* const* d_in, const int* in_sizes, int n_in,
                              void* d_out, int out_size, void* d_ws, size_t ws_size,
                              hipStream_t stream) {
    const float* x       = (const float*)d_in[0];
    const float* W1      = (const float*)d_in[1];
    const float* b1      = (const float*)d_in[2];
    const float* prelu_a = (const float*)d_in[3];
    const float* W2      = (const float*)d_in[4];
    const float* b2      = (const float*)d_in[5];
    const int*   ei      = (const int*)d_in[6];
    const int*   batch   = (const int*)d_in[7];

    const int N = in_sizes[7];          // 100000
    const int E = in_sizes[6] / 2;      // 6400000
    const int* src = ei;
    const int* dst = ei + E;

    // workspace layout (4-byte units), ~35 MB total
    float* ws     = (float*)d_ws;
    float* dinv   = ws;                                        // 100352
    float* h1s    = dinv + 100352;                             // 16N
    float* t2s    = h1s + (size_t)N * HID;                     // 2N
    int*   rowptr = (int*)(t2s + (size_t)N * NOUT);            // 100352
    int*   gcnt   = rowptr + 100352;                           // GCNT_TOT
    unsigned int* bpk = (unsigned int*)(gcnt + GCNT_TOT);      // E (becomes esrc)
    float* partials = (float*)(bpk + E);                       // GB2*PSTRIDE
    int*   bsum   = (int*)(partials + (size_t)GB2 * PSTRIDE);  // SCAN_NB

    float* out = (float*)d_out;

    k_count<<<NCB, 256, 0, stream>>>(dst, gcnt, E);
    k_scan1<<<SCAN_NB, 1024, 0, stream>>>(gcnt, bsum);
    k_scan2<<<1, 128, 0, stream>>>(bsum);
    k_scan3<<<SCAN_NB, 1024, 0, stream>>>(gcnt, bsum);
    k_scatter<<<NCB, 256, 0, stream>>>(src, dst, gcnt, bpk, E);
    k_sort<<<NBUCK, 1024, 0, stream>>>(bpk, gcnt, rowptr, dinv, E, N);
    k_xw1<<<(N + 15) / 16, 256, 0, stream>>>(x, W1, dinv, h1s, N);
    k_gather1<<<(N + 63) / 64, 256, 0, stream>>>((const int*)bpk, rowptr, h1s, dinv, b1, prelu_a, W2, t2s, N);
    k_gather2<<<GB2, 256, 0, stream>>>((const int*)bpk, rowptr, t2s, dinv, batch, partials, N);
    k_final<<<1, 256, 0, stream>>>(partials, b2, out);
}

// Round 7
// 440.196 us; speedup vs baseline: 2.6113x; 1.1712x over previous
//
#include <hip/hip_runtime.h>

#define NFEAT 128
#define HID 16
#define NOUT 2
#define NGRAPH 64

#define BSH 8                      // bucket shift: 256 nodes/bucket
#define BN 256                     // nodes per bucket
#define NBUCK 391                  // ceil(100000/256)
#define NCB 256                    // count/scatter chunk blocks
#define GCNT_TOT (NBUCK * NCB)     // 100096
#define SCAN_NB 98                 // scan blocks: 98*1024 >= GCNT_TOT
#define SCAP 18176                 // staged edges per bucket (71 KB)
#define OVR 8                      // register overflow slots/thread
#define PSTRIDE 192                // 128 graph sums + 64 counts
#define GB2 782                    // gather2 blocks = ceil(100000/128)
#define WST 132                    // sWT row stride (floats): 128+4 pad -> banks spread by h

// ---------------- count: per-(bucket, chunk) histogram ---------------------
__global__ __launch_bounds__(256) void k_count(const int* __restrict__ dst, int* __restrict__ gcnt, int E) {
    __shared__ int c[NBUCK];
    int t = threadIdx.x;
    for (int i = t; i < NBUCK; i += 256) c[i] = 0;
    __syncthreads();
    int chunk = (E + NCB - 1) / NCB;
    int start = blockIdx.x * chunk;
    int end = min(E, start + chunk);
    for (int e = start + t; e < end; e += 256)
        atomicAdd(&c[dst[e] >> BSH], 1);
    __syncthreads();
    for (int i = t; i < NBUCK; i += 256) gcnt[i * NCB + blockIdx.x] = c[i];
}

// ---------------- scan stage 1: block-local exclusive scan + block sums ----
__global__ __launch_bounds__(1024) void k_scan1(int* __restrict__ gcnt, int* __restrict__ bsum) {
    __shared__ int sh[1024];
    int t = threadIdx.x;
    int idx = blockIdx.x * 1024 + t;
    int v = (idx < GCNT_TOT) ? gcnt[idx] : 0;
    sh[t] = v;
    __syncthreads();
    for (int off = 1; off < 1024; off <<= 1) {
        int a = sh[t];
        int b = (t >= off) ? sh[t - off] : 0;
        __syncthreads();
        sh[t] = a + b;
        __syncthreads();
    }
    if (idx < GCNT_TOT) gcnt[idx] = sh[t] - v;     // exclusive within block
    if (t == 1023) bsum[blockIdx.x] = sh[1023];
}

// ---------------- scan stage 2: scan the 98 block sums ---------------------
__global__ __launch_bounds__(128) void k_scan2(int* __restrict__ bsum) {
    __shared__ int sh[128];
    int t = threadIdx.x;
    int v = (t < SCAN_NB) ? bsum[t] : 0;
    sh[t] = v;
    __syncthreads();
    for (int off = 1; off < 128; off <<= 1) {
        int a = sh[t];
        int b = (t >= off) ? sh[t - off] : 0;
        __syncthreads();
        sh[t] = a + b;
        __syncthreads();
    }
    if (t < SCAN_NB) bsum[t] = sh[t] - v;          // exclusive
}

// ---------------- scan stage 3: add block offsets --------------------------
__global__ __launch_bounds__(1024) void k_scan3(int* __restrict__ gcnt, const int* __restrict__ bsum) {
    int idx = blockIdx.x * 1024 + threadIdx.x;
    if (idx < GCNT_TOT) gcnt[idx] += bsum[blockIdx.x];
}

// ---------------- scatter: bucket edges, packed (dloc<<17)|src -------------
__global__ __launch_bounds__(256) void k_scatter(const int* __restrict__ src, const int* __restrict__ dst,
                                                 const int* __restrict__ gcnt,
                                                 unsigned int* __restrict__ bpk, int E) {
    __shared__ int off[NBUCK];
    int t = threadIdx.x;
    for (int i = t; i < NBUCK; i += 256) off[i] = gcnt[i * NCB + blockIdx.x];
    __syncthreads();
    int chunk = (E + NCB - 1) / NCB;
    int start = blockIdx.x * chunk;
    int end = min(E, start + chunk);
    for (int e = start + t; e < end; e += 256) {
        int s = src[e];
        int d = dst[e];
        int kb = d >> BSH;
        int pos = atomicAdd(&off[kb], 1);
        bpk[pos] = ((unsigned)(d & (BN - 1)) << 17) | (unsigned)s;
    }
}

// ---------------- sort: per-bucket counting sort (in place) -> CSR ---------
__global__ __launch_bounds__(1024) void k_sort(unsigned int* __restrict__ bpk, const int* __restrict__ gcnt,
                                               int* __restrict__ rowptr, float* __restrict__ dinv, int E, int N) {
    __shared__ unsigned int stage[SCAP];     // 71 KB
    __shared__ int hist[BN], excl[BN], cur[BN];
    int t = threadIdx.x;
    int k = blockIdx.x;
    int bstart = gcnt[k * NCB];
    int bend = (k < NBUCK - 1) ? gcnt[(k + 1) * NCB] : E;
    int len = bend - bstart;
    int nst = min(len, SCAP);
    if (t < BN) hist[t] = 0;
    for (int j = t; j < nst; j += 1024) stage[j] = bpk[bstart + j];
    unsigned int ov[OVR];
    int nov = 0;
    for (int j = SCAP + t; j < len; j += 1024)
        if (nov < OVR) ov[nov++] = bpk[bstart + j];
    __syncthreads();
    for (int j = t; j < nst; j += 1024) atomicAdd(&hist[stage[j] >> 17], 1);
    for (int i = 0; i < nov; i++) atomicAdd(&hist[ov[i] >> 17], 1);
    __syncthreads();
    if (t < BN) excl[t] = hist[t];
    __syncthreads();
    for (int off = 1; off < BN; off <<= 1) {
        int v = 0;
        if (t < BN && t >= off) v = excl[t - off];
        __syncthreads();
        if (t < BN && t >= off) excl[t] += v;
        __syncthreads();
    }
    if (t < BN) {
        int ex = excl[t] - hist[t];
        cur[t] = ex;
        int node = (k << BSH) + t;
        rowptr[node] = bstart + ex;
        if (node < N) dinv[node] = 1.0f / sqrtf(1.0f + (float)hist[t]);
    }
    __syncthreads();
    for (int j = t; j < nst; j += 1024) {
        unsigned int w = stage[j];
        int r = atomicAdd(&cur[w >> 17], 1);
        bpk[bstart + r] = w & 0x1FFFF;
    }
    for (int i = 0; i < nov; i++) {
        unsigned int w = ov[i];
        int r = atomicAdd(&cur[w >> 17], 1);
        bpk[bstart + r] = w & 0x1FFFF;
    }
}

// ---------------- h1s = dinv * (x @ W1) ------------------------------------
// sWT rows padded to 132 floats: bank = (4h+4k4)%32 -> 2-way (free) vs 16-way
__global__ __launch_bounds__(256) void k_xw1(const float* __restrict__ x, const float* __restrict__ W1,
                                             const float* __restrict__ dinv,
                                             float* __restrict__ h1s, int N) {
    __shared__ float sWT[HID * WST];     // transposed + padded: [h][k], stride 132
    __shared__ float sx[16 * 132];
    int t = threadIdx.x;
    for (int i = t; i < HID * NFEAT; i += 256) {
        int h = i >> 7, kk = i & 127;
        sWT[h * WST + kk] = W1[kk * HID + h];
    }
    int local = t >> 4;
    int h     = t & 15;
    int n = blockIdx.x * 16 + local;
    if (n < N) {
        const float4* xr = (const float4*)(x + (size_t)n * NFEAT);
        float4 a = xr[h * 2];
        float4 b = xr[h * 2 + 1];
        float* sp = sx + local * 132 + h * 8;
        ((float4*)sp)[0] = a;
        ((float4*)sp)[1] = b;
    }
    __syncthreads();
    if (n >= N) return;
    const float4* xr4 = (const float4*)(sx + local * 132);
    const float4* wr4 = (const float4*)(sWT + h * WST);   // 528 B rows, 16B-aligned
    float acc = 0.0f;
    #pragma unroll
    for (int k4 = 0; k4 < 32; k4++) {
        float4 a = xr4[k4];
        float4 b = wr4[k4];
        acc += a.x * b.x + a.y * b.y + a.z * b.z + a.w * b.w;
    }
    h1s[(size_t)n * HID + h] = acc * dinv[n];
}

__device__ __forceinline__ void add4(float4& a, const float4 b) {
    a.x += b.x; a.y += b.y; a.z += b.z; a.w += b.w;
}

// ---------------- gather1: CSR register accumulation -> PReLU -> W2 -> t2s --
__global__ __launch_bounds__(256) void k_gather1(const int* __restrict__ esrc, const int* __restrict__ rowptr,
                                                 const float* __restrict__ h1s, const float* __restrict__ dinv,
                                                 const float* __restrict__ b1, const float* __restrict__ prelu_a,
                                                 const float* __restrict__ W2,
                                                 float* __restrict__ t2s, int N) {
    int t = threadIdx.x;
    int n = blockIdx.x * 64 + (t >> 2);
    int q = t & 3;
    if (n >= N) return;
    const float4* h4 = (const float4*)h1s;
    int r0 = rowptr[n];
    int r1 = rowptr[n + 1];
    float4 acc = h4[(size_t)n * 4 + q];        // self-loop seed
    int i = r0;
    for (; i + 4 <= r1; i += 4) {
        int s0 = esrc[i], s1 = esrc[i + 1], s2 = esrc[i + 2], s3 = esrc[i + 3];
        float4 v0 = h4[(size_t)s0 * 4 + q];
        float4 v1 = h4[(size_t)s1 * 4 + q];
        float4 v2 = h4[(size_t)s2 * 4 + q];
        float4 v3 = h4[(size_t)s3 * 4 + q];
        add4(acc, v0); add4(acc, v1); add4(acc, v2); add4(acc, v3);
    }
    for (; i < r1; i++) add4(acc, h4[(size_t)esrc[i] * 4 + q]);

    float di = dinv[n];
    float a = prelu_a[0];
    float4 bb = ((const float4*)b1)[q];
    float tv0 = di * acc.x + bb.x;
    float tv1 = di * acc.y + bb.y;
    float tv2 = di * acc.z + bb.z;
    float tv3 = di * acc.w + bb.w;
    tv0 = (tv0 >= 0.0f) ? tv0 : a * tv0;
    tv1 = (tv1 >= 0.0f) ? tv1 : a * tv1;
    tv2 = (tv2 >= 0.0f) ? tv2 : a * tv2;
    tv3 = (tv3 >= 0.0f) ? tv3 : a * tv3;
    int rb = q * 4;
    float o0 = tv0 * W2[(rb + 0) * 2] + tv1 * W2[(rb + 1) * 2] + tv2 * W2[(rb + 2) * 2] + tv3 * W2[(rb + 3) * 2];
    float o1 = tv0 * W2[(rb + 0) * 2 + 1] + tv1 * W2[(rb + 1) * 2 + 1] + tv2 * W2[(rb + 2) * 2 + 1] + tv3 * W2[(rb + 3) * 2 + 1];
    o0 += __shfl_xor(o0, 1); o0 += __shfl_xor(o0, 2);
    o1 += __shfl_xor(o1, 1); o1 += __shfl_xor(o1, 2);
    if (q == 0) {
        float2 r = make_float2(di * o0, di * o1);
        *(float2*)(t2s + (size_t)n * 2) = r;
    }
}

// ---------------- gather2 + pool: CSR sum of t2s -> per-graph bins ---------
__global__ __launch_bounds__(256) void k_gather2(const int* __restrict__ esrc, const int* __restrict__ rowptr,
                                                 const float* __restrict__ t2s, const float* __restrict__ dinv,
                                                 const int* __restrict__ batch,
                                                 float* __restrict__ partials, int N) {
    __shared__ float pg[PSTRIDE];
    int t = threadIdx.x;
    if (t < PSTRIDE) pg[t] = 0.0f;
    __syncthreads();
    int n = blockIdx.x * 128 + (t >> 1);
    int c = t & 1;
    if (n < N) {
        int r0 = rowptr[n];
        int r1 = rowptr[n + 1];
        float val = t2s[(size_t)n * 2 + c];    // self-loop
        int i = r0;
        for (; i + 4 <= r1; i += 4) {
            int s0 = esrc[i], s1 = esrc[i + 1], s2 = esrc[i + 2], s3 = esrc[i + 3];
            float v0 = t2s[(size_t)s0 * 2 + c];
            float v1 = t2s[(size_t)s1 * 2 + c];
            float v2 = t2s[(size_t)s2 * 2 + c];
            float v3 = t2s[(size_t)s3 * 2 + c];
            val += (v0 + v1) + (v2 + v3);
        }
        for (; i < r1; i++) val += t2s[(size_t)esrc[i] * 2 + c];
        float dd = dinv[n];
        int g = batch[n];
        atomicAdd(&pg[g * 2 + c], dd * val);
        if (c == 0) atomicAdd(&pg[128 + g], 1.0f);
    }
    __syncthreads();
    if (t < PSTRIDE) partials[(size_t)blockIdx.x * PSTRIDE + t] = pg[t];
}

// ---------------- final: reduce partials, add bias, divide -----------------
__global__ __launch_bounds__(256) void k_final(const float* __restrict__ partials,
                                               const float* __restrict__ b2, float* __restrict__ out) {
    __shared__ float fs[PSTRIDE];
    int t = threadIdx.x;
    if (t < PSTRIDE) {
        float s0 = 0.0f, s1 = 0.0f, s2 = 0.0f, s3 = 0.0f;
        int r = 0;
        for (; r + 4 <= GB2; r += 4) {
            s0 += partials[(size_t)r * PSTRIDE + t];
            s1 += partials[(size_t)(r + 1) * PSTRIDE + t];
            s2 += partials[(size_t)(r + 2) * PSTRIDE + t];
            s3 += partials[(size_t)(r + 3) * PSTRIDE + t];
        }
        for (; r < GB2; r++) s0 += partials[(size_t)r * PSTRIDE + t];
        fs[t] = (s0 + s1) + (s2 + s3);
    }
    __syncthreads();
    if (t < NGRAPH * NOUT) {
        int g = t >> 1, c = t & 1;
        float cnt = fs[128 + g];
        out[t] = (fs[t] + cnt * b2[c]) / fmaxf(cnt, 1.0f);
    }
}

extern "C" void kernel_launch(void* const* d_in, const int* in_sizes, int n_in,
                              void* d_out, int out_size, void* d_ws, size_t ws_size,
                              hipStream_t stream) {
    const float* x       = (const float*)d_in[0];
    const float* W1      = (const float*)d_in[1];
    const float* b1      = (const float*)d_in[2];
    const float* prelu_a = (const float*)d_in[3];
    const float* W2      = (const float*)d_in[4];
    const float* b2      = (const float*)d_in[5];
    const int*   ei      = (const int*)d_in[6];
    const int*   batch   = (const int*)d_in[7];

    const int N = in_sizes[7];          // 100000
    const int E = in_sizes[6] / 2;      // 6400000
    const int* src = ei;
    const int* dst = ei + E;

    // workspace layout (4-byte units), ~35 MB total
    float* ws     = (float*)d_ws;
    float* dinv   = ws;                                        // 100352
    float* h1s    = dinv + 100352;                             // 16N
    float* t2s    = h1s + (size_t)N * HID;                     // 2N
    int*   rowptr = (int*)(t2s + (size_t)N * NOUT);            // 100352
    int*   gcnt   = rowptr + 100352;                           // GCNT_TOT
    unsigned int* bpk = (unsigned int*)(gcnt + GCNT_TOT);      // E (becomes esrc)
    float* partials = (float*)(bpk + E);                       // GB2*PSTRIDE
    int*   bsum   = (int*)(partials + (size_t)GB2 * PSTRIDE);  // SCAN_NB

    float* out = (float*)d_out;

    k_count<<<NCB, 256, 0, stream>>>(dst, gcnt, E);
    k_scan1<<<SCAN_NB, 1024, 0, stream>>>(gcnt, bsum);
    k_scan2<<<1, 128, 0, stream>>>(bsum);
    k_scan3<<<SCAN_NB, 1024, 0, stream>>>(gcnt, bsum);
    k_scatter<<<NCB, 256, 0, stream>>>(src, dst, gcnt, bpk, E);
    k_sort<<<NBUCK, 1024, 0, stream>>>(bpk, gcnt, rowptr, dinv, E, N);
    k_xw1<<<(N + 15) / 16, 256, 0, stream>>>(x, W1, dinv, h1s, N);
    k_gather1<<<(N + 63) / 64, 256, 0, stream>>>((const int*)bpk, rowptr, h1s, dinv, b1, prelu_a, W2, t2s, N);
    k_gather2<<<GB2, 256, 0, stream>>>((const int*)bpk, rowptr, t2s, dinv, batch, partials, N);
    k_final<<<1, 256, 0, stream>>>(partials, b2, out);
}

// Round 8
// 419.553 us; speedup vs baseline: 2.7398x; 1.0492x over previous
//
#include <hip/hip_runtime.h>

#define NFEAT 128
#define HID 16
#define NOUT 2
#define NGRAPH 64

#define BSH 8                      // bucket shift: 256 nodes/bucket
#define BN 256                     // nodes per bucket
#define NBUCK 391                  // ceil(100000/256)
#define NCB 256                    // count/scatter chunk blocks
#define GCNT_TOT (NBUCK * NCB)     // 100096
#define SCAN_NB 98                 // scan blocks: 98*1024 >= GCNT_TOT
#define SCAP 18176                 // staged edges per bucket (71 KB)
#define OVR 8                      // register overflow slots/thread
#define PSTRIDE 192                // 128 graph sums + 64 counts
#define GB2 782                    // gather2 blocks = ceil(100000/128)
#define WST 132                    // sWT row stride (floats): 128+4 pad

typedef unsigned short ushortv8 __attribute__((ext_vector_type(8)));

// RNE float -> bf16 bits
__device__ __forceinline__ unsigned short f2bf(float f) {
    unsigned u = __float_as_uint(f);
    return (unsigned short)((u + 0x7FFFu + ((u >> 16) & 1u)) >> 16);
}

// ---------------- count: per-(bucket, chunk) histogram ---------------------
__global__ __launch_bounds__(256) void k_count(const int* __restrict__ dst, int* __restrict__ gcnt, int E) {
    __shared__ int c[NBUCK];
    int t = threadIdx.x;
    for (int i = t; i < NBUCK; i += 256) c[i] = 0;
    __syncthreads();
    int chunk = (E + NCB - 1) / NCB;
    int start = blockIdx.x * chunk;
    int end = min(E, start + chunk);
    for (int e = start + t; e < end; e += 256)
        atomicAdd(&c[dst[e] >> BSH], 1);
    __syncthreads();
    for (int i = t; i < NBUCK; i += 256) gcnt[i * NCB + blockIdx.x] = c[i];
}

// ---------------- scan stage 1: block-local exclusive scan + block sums ----
__global__ __launch_bounds__(1024) void k_scan1(int* __restrict__ gcnt, int* __restrict__ bsum) {
    __shared__ int sh[1024];
    int t = threadIdx.x;
    int idx = blockIdx.x * 1024 + t;
    int v = (idx < GCNT_TOT) ? gcnt[idx] : 0;
    sh[t] = v;
    __syncthreads();
    for (int off = 1; off < 1024; off <<= 1) {
        int a = sh[t];
        int b = (t >= off) ? sh[t - off] : 0;
        __syncthreads();
        sh[t] = a + b;
        __syncthreads();
    }
    if (idx < GCNT_TOT) gcnt[idx] = sh[t] - v;     // exclusive within block
    if (t == 1023) bsum[blockIdx.x] = sh[1023];
}

// ---------------- scan stage 2: scan the 98 block sums ---------------------
__global__ __launch_bounds__(128) void k_scan2(int* __restrict__ bsum) {
    __shared__ int sh[128];
    int t = threadIdx.x;
    int v = (t < SCAN_NB) ? bsum[t] : 0;
    sh[t] = v;
    __syncthreads();
    for (int off = 1; off < 128; off <<= 1) {
        int a = sh[t];
        int b = (t >= off) ? sh[t - off] : 0;
        __syncthreads();
        sh[t] = a + b;
        __syncthreads();
    }
    if (t < SCAN_NB) bsum[t] = sh[t] - v;          // exclusive
}

// ---------------- scan stage 3: add block offsets --------------------------
__global__ __launch_bounds__(1024) void k_scan3(int* __restrict__ gcnt, const int* __restrict__ bsum) {
    int idx = blockIdx.x * 1024 + threadIdx.x;
    if (idx < GCNT_TOT) gcnt[idx] += bsum[blockIdx.x];
}

// ---------------- scatter: bucket edges, packed (dloc<<17)|src -------------
__global__ __launch_bounds__(256) void k_scatter(const int* __restrict__ src, const int* __restrict__ dst,
                                                 const int* __restrict__ gcnt,
                                                 unsigned int* __restrict__ bpk, int E) {
    __shared__ int off[NBUCK];
    int t = threadIdx.x;
    for (int i = t; i < NBUCK; i += 256) off[i] = gcnt[i * NCB + blockIdx.x];
    __syncthreads();
    int chunk = (E + NCB - 1) / NCB;
    int start = blockIdx.x * chunk;
    int end = min(E, start + chunk);
    for (int e = start + t; e < end; e += 256) {
        int s = src[e];
        int d = dst[e];
        int kb = d >> BSH;
        int pos = atomicAdd(&off[kb], 1);
        bpk[pos] = ((unsigned)(d & (BN - 1)) << 17) | (unsigned)s;
    }
}

// ---------------- sort: per-bucket counting sort (in place) -> CSR ---------
__global__ __launch_bounds__(1024) void k_sort(unsigned int* __restrict__ bpk, const int* __restrict__ gcnt,
                                               int* __restrict__ rowptr, float* __restrict__ dinv, int E, int N) {
    __shared__ unsigned int stage[SCAP];     // 71 KB
    __shared__ int hist[BN], excl[BN], cur[BN];
    int t = threadIdx.x;
    int k = blockIdx.x;
    int bstart = gcnt[k * NCB];
    int bend = (k < NBUCK - 1) ? gcnt[(k + 1) * NCB] : E;
    int len = bend - bstart;
    int nst = min(len, SCAP);
    if (t < BN) hist[t] = 0;
    for (int j = t; j < nst; j += 1024) stage[j] = bpk[bstart + j];
    unsigned int ov[OVR];
    int nov = 0;
    for (int j = SCAP + t; j < len; j += 1024)
        if (nov < OVR) ov[nov++] = bpk[bstart + j];
    __syncthreads();
    for (int j = t; j < nst; j += 1024) atomicAdd(&hist[stage[j] >> 17], 1);
    for (int i = 0; i < nov; i++) atomicAdd(&hist[ov[i] >> 17], 1);
    __syncthreads();
    if (t < BN) excl[t] = hist[t];
    __syncthreads();
    for (int off = 1; off < BN; off <<= 1) {
        int v = 0;
        if (t < BN && t >= off) v = excl[t - off];
        __syncthreads();
        if (t < BN && t >= off) excl[t] += v;
        __syncthreads();
    }
    if (t < BN) {
        int ex = excl[t] - hist[t];
        cur[t] = ex;
        int node = (k << BSH) + t;
        rowptr[node] = bstart + ex;
        if (node < N) dinv[node] = 1.0f / sqrtf(1.0f + (float)hist[t]);
    }
    __syncthreads();
    for (int j = t; j < nst; j += 1024) {
        unsigned int w = stage[j];
        int r = atomicAdd(&cur[w >> 17], 1);
        bpk[bstart + r] = w & 0x1FFFF;
    }
    for (int i = 0; i < nov; i++) {
        unsigned int w = ov[i];
        int r = atomicAdd(&cur[w >> 17], 1);
        bpk[bstart + r] = w & 0x1FFFF;
    }
}

// ---------------- h1b = bf16( dinv * (x @ W1) ) ----------------------------
__global__ __launch_bounds__(256) void k_xw1(const float* __restrict__ x, const float* __restrict__ W1,
                                             const float* __restrict__ dinv,
                                             unsigned short* __restrict__ h1b, int N) {
    __shared__ float sWT[HID * WST];     // transposed + padded: [h][k], stride 132
    __shared__ float sx[16 * 132];
    int t = threadIdx.x;
    for (int i = t; i < HID * NFEAT; i += 256) {
        int h = i >> 7, kk = i & 127;
        sWT[h * WST + kk] = W1[kk * HID + h];
    }
    int local = t >> 4;
    int h     = t & 15;
    int n = blockIdx.x * 16 + local;
    if (n < N) {
        const float4* xr = (const float4*)(x + (size_t)n * NFEAT);
        float4 a = xr[h * 2];
        float4 b = xr[h * 2 + 1];
        float* sp = sx + local * 132 + h * 8;
        ((float4*)sp)[0] = a;
        ((float4*)sp)[1] = b;
    }
    __syncthreads();
    if (n >= N) return;
    const float4* xr4 = (const float4*)(sx + local * 132);
    const float4* wr4 = (const float4*)(sWT + h * WST);
    float acc = 0.0f;
    #pragma unroll
    for (int k4 = 0; k4 < 32; k4++) {
        float4 a = xr4[k4];
        float4 b = wr4[k4];
        acc += a.x * b.x + a.y * b.y + a.z * b.z + a.w * b.w;
    }
    h1b[(size_t)n * HID + h] = f2bf(acc * dinv[n]);   // coalesced 2B/lane
}

__device__ __forceinline__ void acc8(float* acc, ushortv8 v) {
    #pragma unroll
    for (int i = 0; i < 8; i++)
        acc[i] += __uint_as_float(((unsigned)v[i]) << 16);
}

// ---------------- gather1: CSR bf16 gather -> PReLU -> W2 -> t2s -----------
// 2 lanes per node, 16B (8 bf16 feats) each; h1b table is 3.2MB -> L2-resident
__global__ __launch_bounds__(256) void k_gather1(const int* __restrict__ esrc, const int* __restrict__ rowptr,
                                                 const unsigned short* __restrict__ h1b, const float* __restrict__ dinv,
                                                 const float* __restrict__ b1, const float* __restrict__ prelu_a,
                                                 const float* __restrict__ W2,
                                                 float* __restrict__ t2s, int N) {
    int t = threadIdx.x;
    int n = blockIdx.x * 128 + (t >> 1);
    int q = t & 1;
    if (n >= N) return;
    const ushortv8* h8 = (const ushortv8*)h1b;     // 16B granules; row n half q = n*2+q
    int r0 = rowptr[n];
    int r1 = rowptr[n + 1];
    float acc[8] = {0.f, 0.f, 0.f, 0.f, 0.f, 0.f, 0.f, 0.f};
    acc8(acc, h8[(size_t)n * 2 + q]);              // self-loop seed
    int i = r0;
    for (; i + 4 <= r1; i += 4) {
        int s0 = esrc[i], s1 = esrc[i + 1], s2 = esrc[i + 2], s3 = esrc[i + 3];
        ushortv8 v0 = h8[(size_t)s0 * 2 + q];
        ushortv8 v1 = h8[(size_t)s1 * 2 + q];
        ushortv8 v2 = h8[(size_t)s2 * 2 + q];
        ushortv8 v3 = h8[(size_t)s3 * 2 + q];
        acc8(acc, v0); acc8(acc, v1); acc8(acc, v2); acc8(acc, v3);
    }
    for (; i < r1; i++) acc8(acc, h8[(size_t)esrc[i] * 2 + q]);

    float di = dinv[n];
    float a = prelu_a[0];
    float o0 = 0.0f, o1 = 0.0f;
    #pragma unroll
    for (int j = 0; j < 8; j++) {
        int f = q * 8 + j;
        float tv = di * acc[j] + b1[f];
        tv = (tv >= 0.0f) ? tv : a * tv;
        o0 += tv * W2[f * 2 + 0];
        o1 += tv * W2[f * 2 + 1];
    }
    o0 += __shfl_xor(o0, 1);
    o1 += __shfl_xor(o1, 1);
    if (q == 0) {
        *(float2*)(t2s + (size_t)n * 2) = make_float2(di * o0, di * o1);
    }
}

// ---------------- gather2 + pool: CSR sum of t2s -> per-graph bins ---------
__global__ __launch_bounds__(256) void k_gather2(const int* __restrict__ esrc, const int* __restrict__ rowptr,
                                                 const float* __restrict__ t2s, const float* __restrict__ dinv,
                                                 const int* __restrict__ batch,
                                                 float* __restrict__ partials, int N) {
    __shared__ float pg[PSTRIDE];
    int t = threadIdx.x;
    if (t < PSTRIDE) pg[t] = 0.0f;
    __syncthreads();
    int n = blockIdx.x * 128 + (t >> 1);
    int c = t & 1;
    if (n < N) {
        int r0 = rowptr[n];
        int r1 = rowptr[n + 1];
        float val = t2s[(size_t)n * 2 + c];    // self-loop
        int i = r0;
        for (; i + 4 <= r1; i += 4) {
            int s0 = esrc[i], s1 = esrc[i + 1], s2 = esrc[i + 2], s3 = esrc[i + 3];
            float v0 = t2s[(size_t)s0 * 2 + c];
            float v1 = t2s[(size_t)s1 * 2 + c];
            float v2 = t2s[(size_t)s2 * 2 + c];
            float v3 = t2s[(size_t)s3 * 2 + c];
            val += (v0 + v1) + (v2 + v3);
        }
        for (; i < r1; i++) val += t2s[(size_t)esrc[i] * 2 + c];
        float dd = dinv[n];
        int g = batch[n];
        atomicAdd(&pg[g * 2 + c], dd * val);
        if (c == 0) atomicAdd(&pg[128 + g], 1.0f);
    }
    __syncthreads();
    if (t < PSTRIDE) partials[(size_t)blockIdx.x * PSTRIDE + t] = pg[t];
}

// ---------------- final: reduce partials, add bias, divide -----------------
__global__ __launch_bounds__(256) void k_final(const float* __restrict__ partials,
                                               const float* __restrict__ b2, float* __restrict__ out) {
    __shared__ float fs[PSTRIDE];
    int t = threadIdx.x;
    if (t < PSTRIDE) {
        float s0 = 0.0f, s1 = 0.0f, s2 = 0.0f, s3 = 0.0f;
        int r = 0;
        for (; r + 4 <= GB2; r += 4) {
            s0 += partials[(size_t)r * PSTRIDE + t];
            s1 += partials[(size_t)(r + 1) * PSTRIDE + t];
            s2 += partials[(size_t)(r + 2) * PSTRIDE + t];
            s3 += partials[(size_t)(r + 3) * PSTRIDE + t];
        }
        for (; r < GB2; r++) s0 += partials[(size_t)r * PSTRIDE + t];
        fs[t] = (s0 + s1) + (s2 + s3);
    }
    __syncthreads();
    if (t < NGRAPH * NOUT) {
        int g = t >> 1, c = t & 1;
        float cnt = fs[128 + g];
        out[t] = (fs[t] + cnt * b2[c]) / fmaxf(cnt, 1.0f);
    }
}

extern "C" void kernel_launch(void* const* d_in, const int* in_sizes, int n_in,
                              void* d_out, int out_size, void* d_ws, size_t ws_size,
                              hipStream_t stream) {
    const float* x       = (const float*)d_in[0];
    const float* W1      = (const float*)d_in[1];
    const float* b1      = (const float*)d_in[2];
    const float* prelu_a = (const float*)d_in[3];
    const float* W2      = (const float*)d_in[4];
    const float* b2      = (const float*)d_in[5];
    const int*   ei      = (const int*)d_in[6];
    const int*   batch   = (const int*)d_in[7];

    const int N = in_sizes[7];          // 100000
    const int E = in_sizes[6] / 2;      // 6400000
    const int* src = ei;
    const int* dst = ei + E;

    // workspace layout (4-byte units), ~32 MB total
    float* ws     = (float*)d_ws;
    float* dinv   = ws;                                        // 100352
    unsigned short* h1b = (unsigned short*)(dinv + 100352);    // 16N ushorts (= 8N floats)
    float* t2s    = dinv + 100352 + (size_t)N * HID / 2;       // 2N
    int*   rowptr = (int*)(t2s + (size_t)N * NOUT);            // 100352
    int*   gcnt   = rowptr + 100352;                           // GCNT_TOT
    unsigned int* bpk = (unsigned int*)(gcnt + GCNT_TOT);      // E (becomes esrc)
    float* partials = (float*)(bpk + E);                       // GB2*PSTRIDE
    int*   bsum   = (int*)(partials + (size_t)GB2 * PSTRIDE);  // SCAN_NB

    float* out = (float*)d_out;

    k_count<<<NCB, 256, 0, stream>>>(dst, gcnt, E);
    k_scan1<<<SCAN_NB, 1024, 0, stream>>>(gcnt, bsum);
    k_scan2<<<1, 128, 0, stream>>>(bsum);
    k_scan3<<<SCAN_NB, 1024, 0, stream>>>(gcnt, bsum);
    k_scatter<<<NCB, 256, 0, stream>>>(src, dst, gcnt, bpk, E);
    k_sort<<<NBUCK, 1024, 0, stream>>>(bpk, gcnt, rowptr, dinv, E, N);
    k_xw1<<<(N + 15) / 16, 256, 0, stream>>>(x, W1, dinv, h1b, N);
    k_gather1<<<(N + 127) / 128, 256, 0, stream>>>((const int*)bpk, rowptr, h1b, dinv, b1, prelu_a, W2, t2s, N);
    k_gather2<<<GB2, 256, 0, stream>>>((const int*)bpk, rowptr, t2s, dinv, batch, partials, N);
    k_final<<<1, 256, 0, stream>>>(partials, b2, out);
}